// Round 1
// baseline (237.307 us; speedup 1.0000x reference)
//
#include <hip/hip_runtime.h>
#include <math.h>

// Group-limited MoE router, T=131072 tokens x E=256 experts.
// 8 lanes per token, one lane per expert-group (32 experts).
// Round 4: occupancy push. Byte-packed chunk indices (ix[8][4] -> pix[8],
// -24 VGPRs) to get under the 64-VGPR occupancy quantum (4 -> 8 waves/SIMD);
// xor1/2/3 cross-lane via DPP quad_perm (VALU, zero latency) leaving only
// xor4 on the LDS pipe; NEGINF masking replaced by per-round bv gate;
// top-2 scan via v_med3_f32. Sigmoid + all compare orders bit-identical
// to the passing Round-3 kernel.

#define SWZF(x, mask) __int_as_float(__builtin_amdgcn_ds_swizzle(__float_as_int(x), (((mask) << 10) | 0x1F)))
#define SWZI(x, mask) __builtin_amdgcn_ds_swizzle((x), (((mask) << 10) | 0x1F))
// DPP quad_perm codes: xor1 = [1,0,3,2] = 0xB1, xor2 = [2,3,0,1] = 0x4E,
// xor3 = [3,2,1,0] = 0x1B. Each token owns 8 aligned lanes -> quads never
// cross tokens, so quad_perm is safe for xor distances 1..3.
#define DPPF(x, ctrl) __int_as_float(__builtin_amdgcn_update_dpp(__float_as_int(x), __float_as_int(x), (ctrl), 0xF, 0xF, true))
#define DPPI(x, ctrl) __builtin_amdgcn_update_dpp((x), (x), (ctrl), 0xF, 0xF, true)
#define QP_X1 0xB1
#define QP_X2 0x4E
#define QP_X3 0x1B

__global__ __launch_bounds__(256, 8) void router_topk_kernel(
    const float* __restrict__ logits,
    const float* __restrict__ bias,
    float* __restrict__ out_w,
    float* __restrict__ out_id,
    int T)
{
    const float NEGINF = -__builtin_inff();
    const int tid = threadIdx.x;
    const int s = tid & 7;                      // expert-group owned by this lane
    const int token = blockIdx.x * 32 + (tid >> 3);
    if (token >= T) return;

    const float* row = logits + (size_t)token * 256 + s * 32;
    const float* brw = bias + s * 32;

    float    v[8][4];
    unsigned pix[8];   // 4 expert indices per chunk, byte-packed (byte k = idx of v[c][k])

    // ---- load 32 logits, exact sigmoid (matches np ordering), add bias ----
    #pragma unroll
    for (int c = 0; c < 8; ++c) {
        float4 l = ((const float4*)row)[c];
        float4 b = ((const float4*)brw)[c];
        #pragma unroll
        for (int k = 0; k < 4; ++k) {
            float x = (&l.x)[k];
            v[c][k] = 1.0f / (1.0f + expf(-x)) + (&b.x)[k];
        }
        pix[c] = (unsigned)(s * 32 + c * 4) * 0x01010101u + 0x03020100u;
    }

    // ---- group score: sum of top-2 of my 32 biased values (med3 trick) ----
    float t1 = NEGINF, t2 = NEGINF;
    #pragma unroll
    for (int c = 0; c < 8; ++c) {
        #pragma unroll
        for (int k = 0; k < 4; ++k) {
            float val = v[c][k];
            t2 = __builtin_amdgcn_fmed3f(t1, t2, val);  // new 2nd-best (t1>=t2 invariant)
            t1 = fmaxf(t1, val);
        }
    }
    const float gs = t1 + t2;

    // ---- rank my group among the 8; keep top-4 ----
    // xor1/2/3 via DPP; xor4..7 = one swizzle + DPP on its result.
    int rank = 0;
    {
        float g1 = DPPF(gs, QP_X1);
        float g2 = DPPF(gs, QP_X2);
        float g3 = DPPF(gs, QP_X3);
        float g4 = SWZF(gs, 4);
        float g5 = DPPF(g4, QP_X1);
        float g6 = DPPF(g4, QP_X2);
        float g7 = DPPF(g4, QP_X3);
        // partner j = s^m; on tie lower group id wins: j<s iff s has high bit of m.
        rank += (g1 > gs || (g1 == gs && (s & 1))) ? 1 : 0;
        rank += (g2 > gs || (g2 == gs && (s & 2))) ? 1 : 0;
        rank += (g3 > gs || (g3 == gs && (s & 2))) ? 1 : 0;
        rank += (g4 > gs || (g4 == gs && (s & 4))) ? 1 : 0;
        rank += (g5 > gs || (g5 == gs && (s & 4))) ? 1 : 0;
        rank += (g6 > gs || (g6 == gs && (s & 4))) ? 1 : 0;
        rank += (g7 > gs || (g7 == gs && (s & 4))) ? 1 : 0;
    }
    const bool selected = rank < 4;
    // NOTE: no bulk NEGINF masking -- unselected lanes sort/tournament their
    // real values but are gated to NEGINF right before the cross-lane argmax.

    // ---- sort each chunk of 4 descending (ties -> lower idx first) ----
    #pragma unroll
    for (int c = 0; c < 8; ++c) {
        #define CE(A, B, KM) { \
            unsigned p  = pix[c]; \
            unsigned ia = (p >> (8*(A))) & 0xFFu; \
            unsigned ib = (p >> (8*(B))) & 0xFFu; \
            bool sw = (v[c][A] < v[c][B]) || (v[c][A] == v[c][B] && ia > ib); \
            float hv = sw ? v[c][B] : v[c][A]; \
            float lv = sw ? v[c][A] : v[c][B]; \
            v[c][A] = hv; v[c][B] = lv; \
            unsigned ps = (p & (KM)) | (ia << (8*(B))) | (ib << (8*(A))); \
            pix[c] = sw ? ps : p; \
        }
        CE(0,1,0xFFFF0000u) CE(2,3,0x0000FFFFu)
        CE(0,2,0xFF00FF00u) CE(1,3,0x00FF00FFu) CE(1,2,0xFF0000FFu)
        #undef CE
    }

    // ---- 8 rounds: global argmax over 64 stream heads, advance winner ----
    float keepV = 0.0f; int keepI = 0;
    const int sbase8 = s << 3;
    #pragma unroll
    for (int r = 0; r < 8; ++r) {
        // depth-3 tournament over 8 chunk heads; strict > keeps left (lower
        // chunk = lower index) on ties -> lowest-index-first.
        #define PICK(av, ai, bv_, bi_, rv, ri) { \
            bool t = ((bv_) > (av)); \
            rv = t ? (bv_) : (av); ri = t ? (bi_) : (ai); }
        float w0v, w1v, w2v, w3v, x0v, x1v, bv;
        int   w0i, w1i, w2i, w3i, x0i, x1i, bi;
        PICK(v[0][0], (int)(pix[0] & 0xFFu), v[1][0], (int)(pix[1] & 0xFFu), w0v, w0i)
        PICK(v[2][0], (int)(pix[2] & 0xFFu), v[3][0], (int)(pix[3] & 0xFFu), w1v, w1i)
        PICK(v[4][0], (int)(pix[4] & 0xFFu), v[5][0], (int)(pix[5] & 0xFFu), w2v, w2i)
        PICK(v[6][0], (int)(pix[6] & 0xFFu), v[7][0], (int)(pix[7] & 0xFFu), w3v, w3i)
        PICK(w0v, w0i, w1v, w1i, x0v, x0i)
        PICK(w2v, w2i, w3v, w3i, x1v, x1i)
        PICK(x0v, x0i, x1v, x1i, bv, bi)
        #undef PICK
        // gate unselected groups out of the global argmax (replaces 32-wide mask)
        bv = selected ? bv : NEGINF;
        // 8-lane butterfly argmax; index tie-break for cross-lane consistency.
        // xor1/xor2 on DPP (no LDS latency), xor4 on ds_swizzle.
        { float ov = DPPF(bv, QP_X1); int oi = DPPI(bi, QP_X1);
          bool t = (ov > bv) || (ov == bv && oi < bi); bv = t ? ov : bv; bi = t ? oi : bi; }
        { float ov = DPPF(bv, QP_X2); int oi = DPPI(bi, QP_X2);
          bool t = (ov > bv) || (ov == bv && oi < bi); bv = t ? ov : bv; bi = t ? oi : bi; }
        { float ov = SWZF(bv, 4);     int oi = SWZI(bi, 4);
          bool t = (ov > bv) || (ov == bv && oi < bi); bv = t ? ov : bv; bi = t ? oi : bi; }
        if (s == r) { keepV = bv; keepI = bi; }
        const int d = (bi >> 2) - sbase8;   // my chunk index if winner is mine
        #pragma unroll
        for (int c = 0; c < 8; ++c) {
            bool hit = (d == c);
            v[c][0] = hit ? v[c][1] : v[c][0];
            v[c][1] = hit ? v[c][2] : v[c][1];
            v[c][2] = hit ? v[c][3] : v[c][2];
            v[c][3] = hit ? NEGINF  : v[c][3];
            pix[c]  = hit ? (pix[c] >> 8) : pix[c];   // next head index slides to byte 0
        }
    }

    // ---- recover sigmoid score, renormalize, scale, store (coalesced) ----
    float w = keepV - bias[keepI];
    float sum = w;
    sum += DPPF(sum, QP_X1);   // same reduction tree as before: xor1, xor2, xor4
    sum += DPPF(sum, QP_X2);
    sum += SWZF(sum, 4);
    w = w / (sum + 1e-20f) * 2.5f;

    const size_t o = (size_t)blockIdx.x * 256 + tid;  // == token*8 + s
    out_w[o]  = w;
    out_id[o] = (float)keepI;
}

extern "C" void kernel_launch(void* const* d_in, const int* in_sizes, int n_in,
                              void* d_out, int out_size, void* d_ws, size_t ws_size,
                              hipStream_t stream) {
    const float* logits = (const float*)d_in[0];
    const float* bias   = (const float*)d_in[1];
    const int E = in_sizes[1];          // 256
    const int T = in_sizes[0] / E;      // 131072
    float* out_w  = (float*)d_out;
    float* out_id = out_w + (size_t)T * 8;
    const int blocks = (T + 31) / 32;
    router_topk_kernel<<<blocks, 256, 0, stream>>>(logits, bias, out_w, out_id, T);
}

// Round 2
// 207.925 us; speedup vs baseline: 1.1413x; 1.1413x over previous
//
#include <hip/hip_runtime.h>
#include <math.h>

// Group-limited MoE router, T=131072 tokens x E=256 experts.
// 8 lanes per token, one lane per expert-group (32 experts).
// Round 5: same logic as Round 4 (byte-packed pix, DPP quad_perm cross-lane,
// med3 top-2, per-round gating) but WITHOUT the min-waves launch-bounds cap.
// Round 4's __launch_bounds__(256,8) made the compiler cap at 32 VGPRs and
// spill ~32 regs/lane to scratch (WRITE_SIZE 8MB -> 134MB, dur 105us).
// Natural demand with packed indices is ~50 VGPRs; if it lands <=64 the HW
// occupancy quantum gives 8 waves/SIMD without any spill.

#define SWZF(x, mask) __int_as_float(__builtin_amdgcn_ds_swizzle(__float_as_int(x), (((mask) << 10) | 0x1F)))
#define SWZI(x, mask) __builtin_amdgcn_ds_swizzle((x), (((mask) << 10) | 0x1F))
// DPP quad_perm codes: xor1 = [1,0,3,2] = 0xB1, xor2 = [2,3,0,1] = 0x4E,
// xor3 = [3,2,1,0] = 0x1B. Each token owns 8 aligned lanes -> quads never
// cross tokens, so quad_perm is safe for xor distances 1..3.
#define DPPF(x, ctrl) __int_as_float(__builtin_amdgcn_update_dpp(__float_as_int(x), __float_as_int(x), (ctrl), 0xF, 0xF, true))
#define DPPI(x, ctrl) __builtin_amdgcn_update_dpp((x), (x), (ctrl), 0xF, 0xF, true)
#define QP_X1 0xB1
#define QP_X2 0x4E
#define QP_X3 0x1B

__global__ __launch_bounds__(256) void router_topk_kernel(
    const float* __restrict__ logits,
    const float* __restrict__ bias,
    float* __restrict__ out_w,
    float* __restrict__ out_id,
    int T)
{
    const float NEGINF = -__builtin_inff();
    const int tid = threadIdx.x;
    const int s = tid & 7;                      // expert-group owned by this lane
    const int token = blockIdx.x * 32 + (tid >> 3);
    if (token >= T) return;

    const float* row = logits + (size_t)token * 256 + s * 32;
    const float* brw = bias + s * 32;

    float    v[8][4];
    unsigned pix[8];   // 4 expert indices per chunk, byte-packed (byte k = idx of v[c][k])

    // ---- load 32 logits, exact sigmoid (matches np ordering), add bias ----
    #pragma unroll
    for (int c = 0; c < 8; ++c) {
        float4 l = ((const float4*)row)[c];
        float4 b = ((const float4*)brw)[c];
        #pragma unroll
        for (int k = 0; k < 4; ++k) {
            float x = (&l.x)[k];
            v[c][k] = 1.0f / (1.0f + expf(-x)) + (&b.x)[k];
        }
        pix[c] = (unsigned)(s * 32 + c * 4) * 0x01010101u + 0x03020100u;
    }

    // ---- group score: sum of top-2 of my 32 biased values (med3 trick) ----
    float t1 = NEGINF, t2 = NEGINF;
    #pragma unroll
    for (int c = 0; c < 8; ++c) {
        #pragma unroll
        for (int k = 0; k < 4; ++k) {
            float val = v[c][k];
            t2 = __builtin_amdgcn_fmed3f(t1, t2, val);  // new 2nd-best (t1>=t2 invariant)
            t1 = fmaxf(t1, val);
        }
    }
    const float gs = t1 + t2;

    // ---- rank my group among the 8; keep top-4 ----
    // xor1/2/3 via DPP; xor4..7 = one swizzle + DPP on its result.
    int rank = 0;
    {
        float g1 = DPPF(gs, QP_X1);
        float g2 = DPPF(gs, QP_X2);
        float g3 = DPPF(gs, QP_X3);
        float g4 = SWZF(gs, 4);
        float g5 = DPPF(g4, QP_X1);
        float g6 = DPPF(g4, QP_X2);
        float g7 = DPPF(g4, QP_X3);
        // partner j = s^m; on tie lower group id wins: j<s iff s has high bit of m.
        rank += (g1 > gs || (g1 == gs && (s & 1))) ? 1 : 0;
        rank += (g2 > gs || (g2 == gs && (s & 2))) ? 1 : 0;
        rank += (g3 > gs || (g3 == gs && (s & 2))) ? 1 : 0;
        rank += (g4 > gs || (g4 == gs && (s & 4))) ? 1 : 0;
        rank += (g5 > gs || (g5 == gs && (s & 4))) ? 1 : 0;
        rank += (g6 > gs || (g6 == gs && (s & 4))) ? 1 : 0;
        rank += (g7 > gs || (g7 == gs && (s & 4))) ? 1 : 0;
    }
    const bool selected = rank < 4;
    // NOTE: no bulk NEGINF masking -- unselected lanes sort/tournament their
    // real values but are gated to NEGINF right before the cross-lane argmax.

    // ---- sort each chunk of 4 descending (ties -> lower idx first) ----
    #pragma unroll
    for (int c = 0; c < 8; ++c) {
        #define CE(A, B, KM) { \
            unsigned p  = pix[c]; \
            unsigned ia = (p >> (8*(A))) & 0xFFu; \
            unsigned ib = (p >> (8*(B))) & 0xFFu; \
            bool sw = (v[c][A] < v[c][B]) || (v[c][A] == v[c][B] && ia > ib); \
            float hv = sw ? v[c][B] : v[c][A]; \
            float lv = sw ? v[c][A] : v[c][B]; \
            v[c][A] = hv; v[c][B] = lv; \
            unsigned ps = (p & (KM)) | (ia << (8*(B))) | (ib << (8*(A))); \
            pix[c] = sw ? ps : p; \
        }
        CE(0,1,0xFFFF0000u) CE(2,3,0x0000FFFFu)
        CE(0,2,0xFF00FF00u) CE(1,3,0x00FF00FFu) CE(1,2,0xFF0000FFu)
        #undef CE
    }

    // ---- 8 rounds: global argmax over 64 stream heads, advance winner ----
    float keepV = 0.0f; int keepI = 0;
    const int sbase8 = s << 3;
    #pragma unroll
    for (int r = 0; r < 8; ++r) {
        // depth-3 tournament over 8 chunk heads; strict > keeps left (lower
        // chunk = lower index) on ties -> lowest-index-first.
        #define PICK(av, ai, bv_, bi_, rv, ri) { \
            bool t = ((bv_) > (av)); \
            rv = t ? (bv_) : (av); ri = t ? (bi_) : (ai); }
        float w0v, w1v, w2v, w3v, x0v, x1v, bv;
        int   w0i, w1i, w2i, w3i, x0i, x1i, bi;
        PICK(v[0][0], (int)(pix[0] & 0xFFu), v[1][0], (int)(pix[1] & 0xFFu), w0v, w0i)
        PICK(v[2][0], (int)(pix[2] & 0xFFu), v[3][0], (int)(pix[3] & 0xFFu), w1v, w1i)
        PICK(v[4][0], (int)(pix[4] & 0xFFu), v[5][0], (int)(pix[5] & 0xFFu), w2v, w2i)
        PICK(v[6][0], (int)(pix[6] & 0xFFu), v[7][0], (int)(pix[7] & 0xFFu), w3v, w3i)
        PICK(w0v, w0i, w1v, w1i, x0v, x0i)
        PICK(w2v, w2i, w3v, w3i, x1v, x1i)
        PICK(x0v, x0i, x1v, x1i, bv, bi)
        #undef PICK
        // gate unselected groups out of the global argmax (replaces 32-wide mask)
        bv = selected ? bv : NEGINF;
        // 8-lane butterfly argmax; index tie-break for cross-lane consistency.
        // xor1/xor2 on DPP (no LDS latency), xor4 on ds_swizzle.
        { float ov = DPPF(bv, QP_X1); int oi = DPPI(bi, QP_X1);
          bool t = (ov > bv) || (ov == bv && oi < bi); bv = t ? ov : bv; bi = t ? oi : bi; }
        { float ov = DPPF(bv, QP_X2); int oi = DPPI(bi, QP_X2);
          bool t = (ov > bv) || (ov == bv && oi < bi); bv = t ? ov : bv; bi = t ? oi : bi; }
        { float ov = SWZF(bv, 4);     int oi = SWZI(bi, 4);
          bool t = (ov > bv) || (ov == bv && oi < bi); bv = t ? ov : bv; bi = t ? oi : bi; }
        if (s == r) { keepV = bv; keepI = bi; }
        const int d = (bi >> 2) - sbase8;   // my chunk index if winner is mine
        #pragma unroll
        for (int c = 0; c < 8; ++c) {
            bool hit = (d == c);
            v[c][0] = hit ? v[c][1] : v[c][0];
            v[c][1] = hit ? v[c][2] : v[c][1];
            v[c][2] = hit ? v[c][3] : v[c][2];
            v[c][3] = hit ? NEGINF  : v[c][3];
            pix[c]  = hit ? (pix[c] >> 8) : pix[c];   // next head index slides to byte 0
        }
    }

    // ---- recover sigmoid score, renormalize, scale, store (coalesced) ----
    float w = keepV - bias[keepI];
    float sum = w;
    sum += DPPF(sum, QP_X1);   // same reduction tree as before: xor1, xor2, xor4
    sum += DPPF(sum, QP_X2);
    sum += SWZF(sum, 4);
    w = w / (sum + 1e-20f) * 2.5f;

    const size_t o = (size_t)blockIdx.x * 256 + tid;  // == token*8 + s
    out_w[o]  = w;
    out_id[o] = (float)keepI;
}

extern "C" void kernel_launch(void* const* d_in, const int* in_sizes, int n_in,
                              void* d_out, int out_size, void* d_ws, size_t ws_size,
                              hipStream_t stream) {
    const float* logits = (const float*)d_in[0];
    const float* bias   = (const float*)d_in[1];
    const int E = in_sizes[1];          // 256
    const int T = in_sizes[0] / E;      // 131072
    float* out_w  = (float*)d_out;
    float* out_id = out_w + (size_t)T * 8;
    const int blocks = (T + 31) / 32;
    router_topk_kernel<<<blocks, 256, 0, stream>>>(logits, bias, out_w, out_id, T);
}